// Round 10
// baseline (1182.858 us; speedup 1.0000x reference)
//
#include <hip/hip_runtime.h>
#include <hip/hip_bf16.h>

typedef __attribute__((ext_vector_type(8))) short short8;
typedef __attribute__((ext_vector_type(4))) float floatx4;

#define NB 4
#define GRIDD 128
#define GRID3 (128*128*128)
#define C 128
#define KSLOT 32
#define CTX_BPB 256
#define DEN_BLK 1024
#define STAT_BLK 1024
#define PCAP 8192

static __device__ __forceinline__ unsigned short f2bf(float f){
  unsigned u = __builtin_bit_cast(unsigned, f);
  unsigned r = (u + 0x7FFFu + ((u >> 16) & 1u)) >> 16;
  return (unsigned short)r;
}
static __device__ __forceinline__ float bf2f(unsigned short h){
  unsigned u = ((unsigned)h) << 16;
  return __builtin_bit_cast(float, u);
}

// ---------- prep: bf16 conversions + transposes ----------
__global__ void prepk(const float* __restrict__ feats, const float* __restrict__ convw,
                      const float* __restrict__ inw,
                      unsigned short* __restrict__ Fb, unsigned short* __restrict__ Wt,
                      unsigned short* __restrict__ Wq, unsigned short* __restrict__ WkvT,
                      long total1)
{
  const long stride = (long)gridDim.x * blockDim.x;
  const long i0 = (long)blockIdx.x * blockDim.x + threadIdx.x;
  const long q4 = total1 >> 2;
  const float4* f4 = reinterpret_cast<const float4*>(feats);
  ushort4* fb4 = reinterpret_cast<ushort4*>(Fb);
  for (long i = i0; i < q4; i += stride){
    const float4 v = f4[i];
    ushort4 o; o.x = f2bf(v.x); o.y = f2bf(v.y); o.z = f2bf(v.z); o.w = f2bf(v.w);
    fb4[i] = o;
  }
  for (long i = i0; i < 27L*C*C; i += stride){
    long k = i >> 14; long r = (i >> 7) & 127; long c = i & 127;
    Wt[i] = f2bf(convw[(k << 14) + (c << 7) + r]);
  }
  for (long i = i0; i < C*C; i += stride) Wq[i] = f2bf(inw[i]);
  for (long i = i0; i < 2L*C*C; i += stride){
    long which = i >> 14, rem = i & 16383, ii = rem >> 7, cout = rem & 127;
    WkvT[i] = f2bf(inw[((1 + which) << 14) + (cout << 7) + ii]);
  }
}

// ---------- fold W2 = (bw[:, :128]+bw[:, 128:]) @ outw ; b2 = Wcf @ outb ----------
__global__ __launch_bounds__(128) void w2k(const float* __restrict__ bw,
                                           const float* __restrict__ outw,
                                           const float* __restrict__ outb,
                                           unsigned short* __restrict__ W2b,
                                           float* __restrict__ b2){
  const int o = blockIdx.x, i = threadIdx.x;
  __shared__ float wcf[128];
  __shared__ float red[128];
  const float w_i = bw[(size_t)o*256 + i] + bw[(size_t)o*256 + 128 + i];
  wcf[i] = w_i;
  red[i] = w_i * outb[i];
  __syncthreads();
  float acc = 0.f;
  #pragma unroll 8
  for (int j = 0; j < 128; j++) acc = fmaf(wcf[j], outw[j*128 + i], acc);
  W2b[o*128 + i] = f2bf(acc);
  for (int s = 64; s > 0; s >>= 1){
    if (i < s) red[i] += red[i + s];
    __syncthreads();
  }
  if (i == 0) b2[o] = red[0];
}

// ---------- scatter active sites into dense grid hash (grid NOT pre-cleared) ----------
__global__ void scatterk(const int* __restrict__ coords, int* __restrict__ gh, int N){
  int p = blockIdx.x * 256 + threadIdx.x;
  if (p < N){
    int4 cr = *reinterpret_cast<const int4*>(coords + (size_t)p * 4);
    gh[(((cr.x*GRIDD + cr.y)*GRIDD + cr.z)*GRIDD) + cr.w] = p;
  }
}

// ---------- pair lists; coords-validated (garbage-proof), wave-aggregated counts ----------
__global__ __launch_bounds__(256) void pairk(const int* __restrict__ coords,
                                             const int* __restrict__ gh,
                                             int2* __restrict__ pairs,
                                             int* __restrict__ gcnt, int N){
  __shared__ int wcnt[4][27];
  __shared__ int woff[4][27];
  const int t = threadIdx.x, wave = t >> 6, lane = t & 63;
  const int p = blockIdx.x * 256 + t;
  const bool active = p < N;
  int4 cr = make_int4(0, 0, 0, 0);
  if (active) cr = *reinterpret_cast<const int4*>(coords + (size_t)p * 4);
  const int b = cr.x, x = cr.y, y = cr.z, z = cr.w;
  int jl[27];
  #pragma unroll
  for (int k = 0; k < 27; k++){
    jl[k] = -1;
    if (k == 13) continue;
    if (active){
      const int dx = k / 9 - 1, dy = (k / 3) % 3 - 1, dz = k % 3 - 1;
      const int nx = x + dx, ny = y + dy, nz = z + dz;
      if (((unsigned)nx < 128u) & ((unsigned)ny < 128u) & ((unsigned)nz < 128u)){
        const int gi = ((((b << 7) + nx) << 7) + ny) * GRIDD + nz;
        const int jj = gh[gi];
        if ((unsigned)jj < (unsigned)N){
          const int4 cj = *reinterpret_cast<const int4*>(coords + (size_t)jj * 4);
          if (cj.x == b && cj.y == nx && cj.z == ny && cj.w == nz) jl[k] = jj;
        }
      }
    }
  }
  #pragma unroll
  for (int k = 0; k < 27; k++){
    const unsigned long long m = __ballot(jl[k] >= 0);
    if (lane == 0) wcnt[wave][k] = (int)__popcll(m);
  }
  __syncthreads();
  if (t < 27){
    const int c0 = wcnt[0][t], c1 = wcnt[1][t], c2 = wcnt[2][t], c3 = wcnt[3][t];
    const int tot = c0 + c1 + c2 + c3;
    int gb = 0;
    if (t != 13 && tot > 0) gb = atomicAdd(&gcnt[t], tot);
    woff[0][t] = gb;
    woff[1][t] = gb + c0;
    woff[2][t] = gb + c0 + c1;
    woff[3][t] = gb + c0 + c1 + c2;
  }
  __syncthreads();
  const unsigned long long ltm = ((unsigned long long)1 << lane) - 1;
  #pragma unroll
  for (int k = 0; k < 27; k++){
    if (k == 13) continue;
    const unsigned long long m = __ballot(jl[k] >= 0);
    if (jl[k] >= 0){
      const int slot = woff[wave][k] + (int)__popcll(m & ltm);
      if (slot < PCAP) pairs[(size_t)k * PCAP + slot] = make_int2(p, jl[k]);
    }
  }
}

// ---------- off-center scatter-GEMM: Wt[k] in LDS, 16-pair chunks, atomic adds ----------
__global__ __launch_bounds__(256) void scatk(
    const unsigned short* __restrict__ F, const unsigned short* __restrict__ Wt,
    const int2* __restrict__ pairs, const int* __restrict__ gcnt,
    float* __restrict__ X, int N)
{
  __shared__ unsigned short wl[128 * 136];
  const int k = (blockIdx.x < 13) ? blockIdx.x : blockIdx.x + 1;
  const int t = threadIdx.x;
  const unsigned short* wg = Wt + (size_t)k * C * C;
  for (int idx = t; idx < 128 * 16; idx += 256){
    const int row = idx >> 4, seg = idx & 15;
    *reinterpret_cast<short8*>(&wl[row * 136 + seg * 8]) =
        *reinterpret_cast<const short8*>(wg + row * 128 + seg * 8);
  }
  __syncthreads();
  const int cnt = min(gcnt[k], PCAP);
  const int nch = (cnt + 15) >> 4;
  const int wave = t >> 6, lane = t & 63, lo = lane & 15, hi = lane >> 4;
  for (int c = blockIdx.y * 4 + wave; c < nch; c += 32 * 4){
    const int pidx = c * 16 + lo;
    const bool pv = pidx < cnt;
    const int2 pr = pv ? pairs[(size_t)k * PCAP + pidx] : make_int2(0, 0);
    const unsigned short* frow = F + (size_t)pr.y * C;
    short8 a[4];
    #pragma unroll
    for (int kc = 0; kc < 4; kc++){
      a[kc] = *reinterpret_cast<const short8*>(frow + kc * 32 + hi * 8);
      if (!pv) a[kc] = (short8){0,0,0,0,0,0,0,0};
    }
    floatx4 acc[8];
    #pragma unroll
    for (int i = 0; i < 8; i++) acc[i] = (floatx4){0.f,0.f,0.f,0.f};
    #pragma unroll
    for (int kc = 0; kc < 4; kc++){
      const int koff = kc * 32 + hi * 8;
      #pragma unroll
      for (int ct = 0; ct < 8; ct++){
        const short8 b = *reinterpret_cast<const short8*>(&wl[(ct*16 + lo) * 136 + koff]);
        acc[ct] = __builtin_amdgcn_mfma_f32_16x16x32_bf16(a[kc], b, acc[ct], 0, 0, 0);
      }
    }
    #pragma unroll
    for (int i2 = 0; i2 < 4; i2++){
      const int src = hi * 4 + i2;
      const int row = __shfl(pr.x, src);
      if (c * 16 + src < cnt){
        #pragma unroll
        for (int ct = 0; ct < 8; ct++)
          atomicAdd(&X[(size_t)row * C + ct * 16 + lo], acc[ct][i2]);
      }
    }
  }
}

// ---------- denom partials ----------
__global__ __launch_bounds__(256) void denomk(const float* __restrict__ probs,
                                              const int* __restrict__ coords,
                                              float* __restrict__ dpart, int N){
  const int t = threadIdx.x, k = t & 31, rh = t >> 5;
  float a0 = 0.f, a1 = 0.f, a2 = 0.f, a3 = 0.f;
  for (int r = blockIdx.x * 8 + rh; r < N; r += DEN_BLK * 8){
    const int b = coords[(size_t)r * 4];
    const float e = __expf(probs[(size_t)r * 32 + k]);
    a0 += (b == 0) ? e : 0.f;
    a1 += (b == 1) ? e : 0.f;
    a2 += (b == 2) ? e : 0.f;
    a3 += (b == 3) ? e : 0.f;
  }
  __shared__ float ls[8][128];
  ls[rh][0*32 + k] = a0; ls[rh][1*32 + k] = a1;
  ls[rh][2*32 + k] = a2; ls[rh][3*32 + k] = a3;
  __syncthreads();
  if (t < 128){
    float s = 0.f;
    #pragma unroll
    for (int j = 0; j < 8; j++) s += ls[j][t];
    dpart[(size_t)blockIdx.x * 128 + t] = s;
  }
}

// ---------- BN stat partials over f32 xconv + emit bf16 copy ----------
__global__ __launch_bounds__(256) void statsk(const float* __restrict__ X,
                                              float* __restrict__ spgs,
                                              unsigned short* __restrict__ Xb, int N){
  const int t = threadIdx.x, c4 = t & 31, rg = t >> 5;
  float s0=0.f,s1=0.f,s2=0.f,s3=0.f, q0=0.f,q1=0.f,q2=0.f,q3=0.f;
  for (int r = blockIdx.x * 8 + rg; r < N; r += STAT_BLK * 8){
    const float4 v = *reinterpret_cast<const float4*>(X + (size_t)r * C + c4 * 4);
    ushort4 o; o.x = f2bf(v.x); o.y = f2bf(v.y); o.z = f2bf(v.z); o.w = f2bf(v.w);
    *reinterpret_cast<ushort4*>(Xb + (size_t)r * C + c4 * 4) = o;
    s0 += v.x; s1 += v.y; s2 += v.z; s3 += v.w;
    q0 = fmaf(v.x, v.x, q0); q1 = fmaf(v.y, v.y, q1);
    q2 = fmaf(v.z, v.z, q2); q3 = fmaf(v.w, v.w, q3);
  }
  __shared__ float ls[256][4], lq[256][4];
  ls[t][0]=s0; ls[t][1]=s1; ls[t][2]=s2; ls[t][3]=s3;
  lq[t][0]=q0; lq[t][1]=q1; lq[t][2]=q2; lq[t][3]=q3;
  __syncthreads();
  if (t < 32){
    float as[4]={0.f,0.f,0.f,0.f}, aq[4]={0.f,0.f,0.f,0.f};
    #pragma unroll
    for (int g = 0; g < 8; g++){
      #pragma unroll
      for (int j = 0; j < 4; j++){ as[j] += ls[g*32 + t][j]; aq[j] += lq[g*32 + t][j]; }
    }
    #pragma unroll
    for (int j = 0; j < 4; j++){
      spgs[(size_t)blockIdx.x * 256 + t*4 + j] = as[j];
      spgs[(size_t)blockIdx.x * 256 + 128 + t*4 + j] = aq[j];
    }
  }
}

// ---------- reduce partials: which=0 gsum, 1 gsq, 2 denom ----------
__global__ __launch_bounds__(128) void reduk(const float* __restrict__ pgs,
                                             const float* __restrict__ dpart,
                                             float* __restrict__ gsum,
                                             float* __restrict__ gsq,
                                             float* __restrict__ denom){
  const int which = blockIdx.x, slice = blockIdx.y, t = threadIdx.x;
  float s = 0.f;
  if (which < 2){
    const float* src = pgs + which * 128 + t;
    for (int j = slice; j < STAT_BLK; j += 8) s += src[(size_t)j * 256];
    atomicAdd((which ? gsq : gsum) + t, s);
  } else {
    const float* src = dpart + t;
    for (int j = slice; j < DEN_BLK; j += 8) s += src[(size_t)j * 128];
    atomicAdd(denom + t, s);
  }
}

// ---------- finalize BN scale/shift + inverse denominators ----------
__global__ void finalizek(const float* __restrict__ sums, const float* __restrict__ sumsq,
                          const float* __restrict__ gamma, const float* __restrict__ beta,
                          const float* __restrict__ denom,
                          float* __restrict__ scalev, float* __restrict__ shiftv,
                          float* __restrict__ invden, int N){
  const int t = threadIdx.x;   // 128
  const float invN = 1.f / (float)N;
  const float mu = sums[t] * invN;
  const float var = sumsq[t] * invN - mu * mu;
  const float sc = gamma[t] * rsqrtf(var + 1e-5f);
  scalev[t] = sc;
  shiftv[t] = beta[t] - mu * sc;
  invden[t] = 1.f / denom[t];
}

// ---------- ctx partials v3: bf16 x tiles staged to LDS as f32, exp recomputed ----------
__global__ __launch_bounds__(256) void ctx2k(const unsigned short* __restrict__ Xb,
                                             const float* __restrict__ probs,
                                             const float* __restrict__ scalev,
                                             const float* __restrict__ shiftv,
                                             float* __restrict__ pbuf, int NPER){
  __shared__ float xL[32 * 128];       // 16 KB x tile (converted to f32)
  __shared__ float pe[32 * 32];        // 4 KB exp(probs) tile
  __shared__ float red[2 * KSLOT * C]; // 32 KB reduction
  const int blk = blockIdx.x;
  const int b = blk >> 8, j = blk & 255;
  const int rows = (NPER + CTX_BPB - 1) / CTX_BPB;
  const int r0 = j * rows;
  const int r1 = min(r0 + rows, NPER);
  const int t = threadIdx.x, c = t & 127, rh = t >> 7;
  const float sc = scalev[c], sh = shiftv[c];
  float acc[KSLOT];
  #pragma unroll
  for (int k = 0; k < KSLOT; k++) acc[k] = 0.f;

  for (int base = r0; base < r1; base += 32){
    __syncthreads();
    // stage bf16 x tile: 512 short8 loads, 2 per thread, independent coalesced
    #pragma unroll
    for (int i = 0; i < 2; i++){
      const int idx = i * 256 + t;
      const int r = idx >> 4, c8 = idx & 15;
      const int rr = base + r;
      short8 v = (short8){0,0,0,0,0,0,0,0};
      if (rr < r1) v = *reinterpret_cast<const short8*>(Xb + ((size_t)b * NPER + rr) * C + c8 * 8);
      float4 f0, f1;
      f0.x = bf2f((unsigned short)v[0]); f0.y = bf2f((unsigned short)v[1]);
      f0.z = bf2f((unsigned short)v[2]); f0.w = bf2f((unsigned short)v[3]);
      f1.x = bf2f((unsigned short)v[4]); f1.y = bf2f((unsigned short)v[5]);
      f1.z = bf2f((unsigned short)v[6]); f1.w = bf2f((unsigned short)v[7]);
      *reinterpret_cast<float4*>(&xL[r * 128 + c8 * 8]) = f0;
      *reinterpret_cast<float4*>(&xL[r * 128 + c8 * 8 + 4]) = f1;
    }
    // stage exp(probs) tile
    {
      const int r = t >> 3, k4 = t & 7;
      const int rr = base + r;
      float4 v = make_float4(0.f, 0.f, 0.f, 0.f);
      if (rr < r1){
        const float4 pv = *reinterpret_cast<const float4*>(probs + ((size_t)b * NPER + rr) * 32 + k4 * 4);
        v.x = __expf(pv.x); v.y = __expf(pv.y); v.z = __expf(pv.z); v.w = __expf(pv.w);
      }
      *reinterpret_cast<float4*>(&pe[r * 32 + k4 * 4]) = v;
    }
    __syncthreads();
    const int rend = min(32, r1 - base);
    for (int r = rh; r < rend; r += 2){
      const float xv = fmaxf(fmaf(xL[r * 128 + c], sc, sh), 0.f);
      const float4* wr = reinterpret_cast<const float4*>(&pe[r * 32]);
      #pragma unroll
      for (int kq = 0; kq < 8; kq++){
        const float4 w4 = wr[kq];
        acc[kq*4+0] = fmaf(w4.x, xv, acc[kq*4+0]);
        acc[kq*4+1] = fmaf(w4.y, xv, acc[kq*4+1]);
        acc[kq*4+2] = fmaf(w4.z, xv, acc[kq*4+2]);
        acc[kq*4+3] = fmaf(w4.w, xv, acc[kq*4+3]);
      }
    }
  }
  __syncthreads();
  #pragma unroll
  for (int k = 0; k < KSLOT; k++) red[(rh * KSLOT + k) * C + c] = acc[k];
  __syncthreads();
  float* dst = pbuf + (size_t)blk * KSLOT * C;
  for (int i = t; i < KSLOT * C; i += 256) dst[i] = red[i] + red[KSLOT * C + i];
}

// ---------- kv: reduce ctx partials then project ----------
__global__ __launch_bounds__(256) void kvk(const float* __restrict__ pbuf,
                                           const float* __restrict__ invden,
                                           const unsigned short* __restrict__ WkvT,
                                           const float* __restrict__ inb,
                                           float* __restrict__ kh, float* __restrict__ vh){
  __shared__ float rowp[2][C];
  __shared__ float row[C];
  const int bk = blockIdx.x;              // b*32 + k
  const int b = bk >> 5, k = bk & 31;
  const int t = threadIdx.x, c = t & 127, jh = t >> 7;
  float s = 0.f;
  for (int j = jh; j < CTX_BPB; j += 2)
    s += pbuf[((size_t)(b * CTX_BPB + j) * KSLOT + k) * C + c];
  rowp[jh][c] = s;
  __syncthreads();
  if (t < C) row[t] = (rowp[0][t] + rowp[1][t]) * invden[b * KSLOT + k];
  __syncthreads();
  const int which = t >> 7;
  const unsigned short* W = WkvT + (size_t)which * C * C;
  float acc = inb[(1 + which) * C + c];
  #pragma unroll 8
  for (int i = 0; i < C; i++) acc = fmaf(row[i], bf2f(W[i * C + c]), acc);
  (which ? vh : kh)[(size_t)bk * C + c] = acc;
}

// ---------- N x 128 @ (128x128)^T bf16 MFMA GEMM ----------
__global__ __launch_bounds__(256) void gemm128(
    const unsigned short* __restrict__ A, const unsigned short* __restrict__ W,
    const float* __restrict__ bias, float scale,
    float* __restrict__ outF, unsigned short* __restrict__ outB, int N)
{
  const int tid = threadIdx.x;
  const int wave = tid >> 6, lane = tid & 63;
  const int rbase = blockIdx.x * 64 + (wave >> 1) * 32;
  const int cbase = (wave & 1) * 64;
  const int lo = lane & 15, hi = lane >> 4;
  floatx4 acc[2][4];
  #pragma unroll
  for (int rt = 0; rt < 2; rt++)
    #pragma unroll
    for (int ct = 0; ct < 4; ct++) acc[rt][ct] = (floatx4){0.f,0.f,0.f,0.f};
  const int m0 = rbase + lo, m1 = rbase + 16 + lo;
  const int m0c = m0 < N ? m0 : N - 1;
  const int m1c = m1 < N ? m1 : N - 1;
  #pragma unroll
  for (int kc = 0; kc < 4; kc++){
    const int koff = kc * 32 + hi * 8;
    const short8 a0 = *reinterpret_cast<const short8*>(A + (size_t)m0c * C + koff);
    const short8 a1 = *reinterpret_cast<const short8*>(A + (size_t)m1c * C + koff);
    #pragma unroll
    for (int ct = 0; ct < 4; ct++){
      const int n = cbase + ct * 16 + lo;
      const short8 b = *reinterpret_cast<const short8*>(W + (size_t)n * C + koff);
      acc[0][ct] = __builtin_amdgcn_mfma_f32_16x16x32_bf16(a0, b, acc[0][ct], 0, 0, 0);
      acc[1][ct] = __builtin_amdgcn_mfma_f32_16x16x32_bf16(a1, b, acc[1][ct], 0, 0, 0);
    }
  }
  #pragma unroll
  for (int rt = 0; rt < 2; rt++){
    #pragma unroll
    for (int ct = 0; ct < 4; ct++){
      const int col = cbase + ct * 16 + lo;
      const float bv = bias ? bias[col] : 0.f;
      #pragma unroll
      for (int i = 0; i < 4; i++){
        const int row = rbase + rt * 16 + hi * 4 + i;
        if (row < N){
          const float v = (acc[rt][ct][i] + bv) * scale;
          if (outF) outF[(size_t)row * C + col] = v;
          if (outB) outB[(size_t)row * C + col] = f2bf(v);
        }
      }
    }
  }
}

// ---------- bf16-A variant with inline BN+ReLU (for q projection) ----------
__global__ __launch_bounds__(256) void gemm128b(
    const unsigned short* __restrict__ A, const unsigned short* __restrict__ W,
    const float* __restrict__ bias, const float* __restrict__ bnsc,
    const float* __restrict__ bnsh, float scale,
    unsigned short* __restrict__ outB, int N)
{
  const int tid = threadIdx.x;
  const int wave = tid >> 6, lane = tid & 63;
  const int rbase = blockIdx.x * 64 + (wave >> 1) * 32;
  const int cbase = (wave & 1) * 64;
  const int lo = lane & 15, hi = lane >> 4;
  floatx4 acc[2][4];
  #pragma unroll
  for (int rt = 0; rt < 2; rt++)
    #pragma unroll
    for (int ct = 0; ct < 4; ct++) acc[rt][ct] = (floatx4){0.f,0.f,0.f,0.f};
  const int m0 = rbase + lo, m1 = rbase + 16 + lo;
  const int m0c = m0 < N ? m0 : N - 1;
  const int m1c = m1 < N ? m1 : N - 1;
  #pragma unroll
  for (int kc = 0; kc < 4; kc++){
    const int koff = kc * 32 + hi * 8;
    short8 a0 = *reinterpret_cast<const short8*>(A + (size_t)m0c * C + koff);
    short8 a1 = *reinterpret_cast<const short8*>(A + (size_t)m1c * C + koff);
    #pragma unroll
    for (int j = 0; j < 8; j++){
      const float scj = bnsc[koff + j], shj = bnsh[koff + j];
      a0[j] = (short)f2bf(fmaxf(fmaf(bf2f((unsigned short)a0[j]), scj, shj), 0.f));
      a1[j] = (short)f2bf(fmaxf(fmaf(bf2f((unsigned short)a1[j]), scj, shj), 0.f));
    }
    #pragma unroll
    for (int ct = 0; ct < 4; ct++){
      const int n = cbase + ct * 16 + lo;
      const short8 b = *reinterpret_cast<const short8*>(W + (size_t)n * C + koff);
      acc[0][ct] = __builtin_amdgcn_mfma_f32_16x16x32_bf16(a0, b, acc[0][ct], 0, 0, 0);
      acc[1][ct] = __builtin_amdgcn_mfma_f32_16x16x32_bf16(a1, b, acc[1][ct], 0, 0, 0);
    }
  }
  #pragma unroll
  for (int rt = 0; rt < 2; rt++){
    #pragma unroll
    for (int ct = 0; ct < 4; ct++){
      const int col = cbase + ct * 16 + lo;
      const float bv = bias[col];
      #pragma unroll
      for (int i = 0; i < 4; i++){
        const int row = rbase + rt * 16 + hi * 4 + i;
        if (row < N) outB[(size_t)row * C + col] = f2bf((acc[rt][ct][i] + bv) * scale);
      }
    }
  }
}

// ---------- attention v4: 2 rows/thread share each LDS k/v read ----------
__global__ __launch_bounds__(256) void attn4k(const unsigned short* __restrict__ qb,
                                              const float* __restrict__ kh,
                                              const float* __restrict__ vh,
                                              unsigned short* __restrict__ ob, int NPER){
  __shared__ float khL[KSLOT * C];
  __shared__ float vhL[KSLOT * C];
  const int t = threadIdx.x;
  const int b = blockIdx.y;
  const int n0 = blockIdx.x * 64;
  {
    const float4* ks = reinterpret_cast<const float4*>(kh + (size_t)b * KSLOT * C);
    const float4* vs = reinterpret_cast<const float4*>(vh + (size_t)b * KSLOT * C);
    float4* kd = reinterpret_cast<float4*>(khL);
    float4* vd = reinterpret_cast<float4*>(vhL);
    #pragma unroll
    for (int i = 0; i < 4; i++){ kd[i * 256 + t] = ks[i * 256 + t]; vd[i * 256 + t] = vs[i * 256 + t]; }
  }
  __syncthreads();
  const int h = t >> 5, p = t & 31;
  const int na = n0 + p, nb = n0 + 32 + p;
  const int nac = na < NPER ? na : NPER - 1;
  const int nbc = nb < NPER ? nb : NPER - 1;
  float qa[16], qv[16];
  {
    const short8* qp = reinterpret_cast<const short8*>(qb + ((size_t)b * NPER + nac) * C + h * 16);
    const short8 x0 = qp[0], x1 = qp[1];
    const short8* qq = reinterpret_cast<const short8*>(qb + ((size_t)b * NPER + nbc) * C + h * 16);
    const short8 y0 = qq[0], y1 = qq[1];
    #pragma unroll
    for (int i = 0; i < 8; i++){
      qa[i] = bf2f((unsigned short)x0[i]); qa[8+i] = bf2f((unsigned short)x1[i]);
      qv[i] = bf2f((unsigned short)y0[i]); qv[8+i] = bf2f((unsigned short)y1[i]);
    }
  }
  float sa[KSLOT], sb[KSLOT];
  #pragma unroll
  for (int k = 0; k < KSLOT; k++){
    const float4* kp = reinterpret_cast<const float4*>(&khL[k * C + h * 16]);
    const float4 k0 = kp[0], k1 = kp[1], k2 = kp[2], k3 = kp[3];
    const float* kf = &k0.x;   // consecutive f4 in regs
    float s0 = 0.f, s1 = 0.f;
    s0 = fmaf(qa[0], k0.x, s0); s1 = fmaf(qv[0], k0.x, s1);
    s0 = fmaf(qa[1], k0.y, s0); s1 = fmaf(qv[1], k0.y, s1);
    s0 = fmaf(qa[2], k0.z, s0); s1 = fmaf(qv[2], k0.z, s1);
    s0 = fmaf(qa[3], k0.w, s0); s1 = fmaf(qv[3], k0.w, s1);
    s0 = fmaf(qa[4], k1.x, s0); s1 = fmaf(qv[4], k1.x, s1);
    s0 = fmaf(qa[5], k1.y, s0); s1 = fmaf(qv[5], k1.y, s1);
    s0 = fmaf(qa[6], k1.z, s0); s1 = fmaf(qv[6], k1.z, s1);
    s0 = fmaf(qa[7], k1.w, s0); s1 = fmaf(qv[7], k1.w, s1);
    s0 = fmaf(qa[8], k2.x, s0); s1 = fmaf(qv[8], k2.x, s1);
    s0 = fmaf(qa[9], k2.y, s0); s1 = fmaf(qv[9], k2.y, s1);
    s0 = fmaf(qa[10], k2.z, s0); s1 = fmaf(qv[10], k2.z, s1);
    s0 = fmaf(qa[11], k2.w, s0); s1 = fmaf(qv[11], k2.w, s1);
    s0 = fmaf(qa[12], k3.x, s0); s1 = fmaf(qv[12], k3.x, s1);
    s0 = fmaf(qa[13], k3.y, s0); s1 = fmaf(qv[13], k3.y, s1);
    s0 = fmaf(qa[14], k3.z, s0); s1 = fmaf(qv[14], k3.z, s1);
    s0 = fmaf(qa[15], k3.w, s0); s1 = fmaf(qv[15], k3.w, s1);
    (void)kf;
    sa[k] = s0; sb[k] = s1;
  }
  float ma = sa[0], mb = sb[0];
  #pragma unroll
  for (int k = 1; k < KSLOT; k++){ ma = fmaxf(ma, sa[k]); mb = fmaxf(mb, sb[k]); }
  float suma = 0.f, sumb = 0.f;
  #pragma unroll
  for (int k = 0; k < KSLOT; k++){
    const float ea = __expf(sa[k] - ma); sa[k] = ea; suma += ea;
    const float eb = __expf(sb[k] - mb); sb[k] = eb; sumb += eb;
  }
  const float inva = 1.f / suma, invb = 1.f / sumb;
  float oa[16], obv[16];
  #pragma unroll
  for (int i = 0; i < 16; i++){ oa[i] = 0.f; obv[i] = 0.f; }
  #pragma unroll
  for (int k = 0; k < KSLOT; k++){
    const float wa = sa[k], wb = sb[k];
    const float4* vp = reinterpret_cast<const float4*>(&vhL[k * C + h * 16]);
    const float4 v0 = vp[0], v1 = vp[1], v2 = vp[2], v3 = vp[3];
    oa[0]  = fmaf(wa, v0.x, oa[0]);  obv[0]  = fmaf(wb, v0.x, obv[0]);
    oa[1]  = fmaf(wa, v0.y, oa[1]);  obv[1]  = fmaf(wb, v0.y, obv[1]);
    oa[2]  = fmaf(wa, v0.z, oa[2]);  obv[2]  = fmaf(wb, v0.z, obv[2]);
    oa[3]  = fmaf(wa, v0.w, oa[3]);  obv[3]  = fmaf(wb, v0.w, obv[3]);
    oa[4]  = fmaf(wa, v1.x, oa[4]);  obv[4]  = fmaf(wb, v1.x, obv[4]);
    oa[5]  = fmaf(wa, v1.y, oa[5]);  obv[5]  = fmaf(wb, v1.y, obv[5]);
    oa[6]  = fmaf(wa, v1.z, oa[6]);  obv[6]  = fmaf(wb, v1.z, obv[6]);
    oa[7]  = fmaf(wa, v1.w, oa[7]);  obv[7]  = fmaf(wb, v1.w, obv[7]);
    oa[8]  = fmaf(wa, v2.x, oa[8]);  obv[8]  = fmaf(wb, v2.x, obv[8]);
    oa[9]  = fmaf(wa, v2.y, oa[9]);  obv[9]  = fmaf(wb, v2.y, obv[9]);
    oa[10] = fmaf(wa, v2.z, oa[10]); obv[10] = fmaf(wb, v2.z, obv[10]);
    oa[11] = fmaf(wa, v2.w, oa[11]); obv[11] = fmaf(wb, v2.w, obv[11]);
    oa[12] = fmaf(wa, v3.x, oa[12]); obv[12] = fmaf(wb, v3.x, obv[12]);
    oa[13] = fmaf(wa, v3.y, oa[13]); obv[13] = fmaf(wb, v3.y, obv[13]);
    oa[14] = fmaf(wa, v3.z, oa[14]); obv[14] = fmaf(wb, v3.z, obv[14]);
    oa[15] = fmaf(wa, v3.w, oa[15]); obv[15] = fmaf(wb, v3.w, obv[15]);
  }
  if (na < NPER){
    short8 s0, s1;
    #pragma unroll
    for (int i = 0; i < 8; i++){
      s0[i] = (short)f2bf(oa[i] * inva);
      s1[i] = (short)f2bf(oa[8 + i] * inva);
    }
    unsigned short* op = ob + ((size_t)b * NPER + na) * C + h * 16;
    *reinterpret_cast<short8*>(op) = s0;
    *reinterpret_cast<short8*>(op + 8) = s1;
  }
  if (nb < NPER){
    short8 s0, s1;
    #pragma unroll
    for (int i = 0; i < 8; i++){
      s0[i] = (short)f2bf(obv[i] * invb);
      s1[i] = (short)f2bf(obv[8 + i] * invb);
    }
    unsigned short* op = ob + ((size_t)b * NPER + nb) * C + h * 16;
    *reinterpret_cast<short8*>(op) = s0;
    *reinterpret_cast<short8*>(op + 8) = s1;
  }
}

extern "C" void kernel_launch(void* const* d_in, const int* in_sizes, int n_in,
                              void* d_out, int out_size, void* d_ws, size_t ws_size,
                              hipStream_t stream){
  const float* feats  = (const float*)d_in[0];
  const float* probs  = (const float*)d_in[1];
  const float* convw  = (const float*)d_in[2];
  const float* gamma  = (const float*)d_in[3];
  const float* beta   = (const float*)d_in[4];
  const float* inw    = (const float*)d_in[5];
  const float* inb    = (const float*)d_in[6];
  const float* outw   = (const float*)d_in[7];
  const float* outb   = (const float*)d_in[8];
  const float* bw     = (const float*)d_in[9];
  const int*   coords = (const int*)d_in[10];
  const int N = in_sizes[0] / C;
  const int NPER = N / NB;
  const int NBLK = (N + 63) / 64;

  char* ws = (char*)d_ws;
  size_t off = 0;
  auto alloc = [&](size_t bytes) -> char* {
    char* r = ws + off; off += (bytes + 255) & ~(size_t)255; return r;
  };
  int* grid_h            = (int*)alloc((size_t)NB * GRID3 * 4);          // 33.5 MB
  unsigned short* featsb = (unsigned short*)alloc((size_t)N * C * 2);    // 25.6 MB
  unsigned short* convwt = (unsigned short*)alloc((size_t)27 * C * C * 2);
  unsigned short* wq     = (unsigned short*)alloc((size_t)C * C * 2);
  unsigned short* wkvT   = (unsigned short*)alloc((size_t)2 * C * C * 2);
  unsigned short* w2b    = (unsigned short*)alloc((size_t)C * C * 2);
  float* b2              = (float*)alloc(512);
  float* xconv           = (float*)alloc((size_t)N * C * 4);             // 51.2 MB
  unsigned short* qb     = (unsigned short*)alloc((size_t)N * C * 2);    // 25.6 MB
  int2* pairs            = (int2*)alloc((size_t)27 * PCAP * 8);
  float* spgs            = (float*)alloc((size_t)STAT_BLK * 256 * 4);
  float* dpart           = (float*)alloc((size_t)DEN_BLK * 128 * 4);
  float* zero_base       = (float*)alloc((size_t)512 * 4);
  float* gsum   = zero_base;
  float* gsq    = zero_base + 128;
  float* denom  = zero_base + 256;
  int*   gcnt   = (int*)(zero_base + 384);
  float* invden = (float*)alloc(512);
  float* scalev = (float*)alloc(512);
  float* shiftv = (float*)alloc(512);
  float* kh     = (float*)alloc((size_t)NB * KSLOT * C * 4);
  float* vh     = (float*)alloc((size_t)NB * KSLOT * C * 4);
  // aliases (lifetimes disjoint):
  float* pbuf = (float*)grid_h;                  // grid dead after pairk; 16.8 <= 33.5 MB
  unsigned short* xbf  = featsb;                 // featsb dead after scatk -> bf16 x copy
  unsigned short* o_bf = featsb;                 // xbf dead after gemm128b -> attn output

  (void)hipMemsetAsync(zero_base, 0, (size_t)512 * 4, stream);
  prepk<<<2048, 256, 0, stream>>>(feats, convw, inw, featsb, convwt, wq, wkvT, (long)N * C);
  w2k<<<128, 128, 0, stream>>>(bw, outw, outb, w2b, b2);
  scatterk<<<(N + 255) / 256, 256, 0, stream>>>(coords, grid_h, N);
  pairk<<<(N + 255) / 256, 256, 0, stream>>>(coords, grid_h, pairs, gcnt, N);
  denomk<<<DEN_BLK, 256, 0, stream>>>(probs, coords, dpart, N);
  gemm128<<<NBLK, 256, 0, stream>>>(featsb, convwt + 13 * C * C, nullptr, 1.f, xconv, nullptr, N);
  scatk<<<dim3(26, 32), 256, 0, stream>>>(featsb, convwt, pairs, gcnt, xconv, N);
  // featsb dead; statsk writes bf16 copy into it
  statsk<<<STAT_BLK, 256, 0, stream>>>(xconv, spgs, xbf, N);
  {
    dim3 rg(3, 8);
    reduk<<<rg, 128, 0, stream>>>(spgs, dpart, gsum, gsq, denom);
  }
  finalizek<<<1, 128, 0, stream>>>(gsum, gsq, gamma, beta, denom, scalev, shiftv, invden, N);
  ctx2k<<<NB * CTX_BPB, 256, 0, stream>>>(xbf, probs, scalev, shiftv, pbuf, NPER);
  kvk<<<NB * KSLOT, 256, 0, stream>>>(pbuf, invden, wkvT, inb, kh, vh);
  gemm128b<<<NBLK, 256, 0, stream>>>(xbf, wq, inb, scalev, shiftv, 0.25f, qb, N);
  dim3 agrid((NPER + 63) / 64, NB);
  attn4k<<<agrid, 256, 0, stream>>>(qb, kh, vh, o_bf, NPER);
  gemm128<<<NBLK, 256, 0, stream>>>(o_bf, w2b, b2, 1.f, (float*)d_out, nullptr, N);
}